// Round 7
// baseline (377.667 us; speedup 1.0000x reference)
//
#include <hip/hip_runtime.h>
#include <math.h>

#define NODES  50000
#define EDGES  800000
#define GRAPHS 256
#define FEAT   128
#define STATE  64
#define M_OUT  32
#define ROUNDS 4
#define NT32   ((NODES + 31) / 32)     // 1563 tiles of 32 nodes (dense kernels)
#define NT64   ((NODES + 63) / 64)     // 782 tiles of 64 nodes (gather halves)
#define HALF   32                      // features per plane
#define CAP    64                      // fixed csr bucket capacity (deg~Poisson(16), max~38)
#define CROW   72                      // padded LDS row stride (u16) -- kills bank conflicts
#define OVFMAX 8192                    // overflow list capacity (expected use: 0)

typedef unsigned short bfraw;

__device__ __forceinline__ bfraw f2bf(float f) {
    union { float f; unsigned int i; } v; v.f = f;
    unsigned int r = v.i + 0x7FFF + ((v.i >> 16) & 1); // round-nearest-even
    return (bfraw)(r >> 16);
}
__device__ __forceinline__ int packbf(float lo, float hi) {
    return ((int)f2bf(hi) << 16) | (int)f2bf(lo);
}
__device__ __forceinline__ void addv8(float* acc, int4 v, float m) {
    union { int i; float f; } t;
    t.i = v.x << 16;                  acc[0] += t.f * m;
    t.i = v.x & (int)0xffff0000;      acc[1] += t.f * m;
    t.i = v.y << 16;                  acc[2] += t.f * m;
    t.i = v.y & (int)0xffff0000;      acc[3] += t.f * m;
    t.i = v.z << 16;                  acc[4] += t.f * m;
    t.i = v.z & (int)0xffff0000;      acc[5] += t.f * m;
    t.i = v.w << 16;                  acc[6] += t.f * m;
    t.i = v.w & (int)0xffff0000;      acc[7] += t.f * m;
}
__device__ __forceinline__ void unpack8(float* d, int4 v) {
    union { int i; float f; } t;
    t.i = v.x << 16;              d[0] = t.f;
    t.i = v.x & (int)0xffff0000;  d[1] = t.f;
    t.i = v.y << 16;              d[2] = t.f;
    t.i = v.y & (int)0xffff0000;  d[3] = t.f;
    t.i = v.z << 16;              d[4] = t.f;
    t.i = v.z & (int)0xffff0000;  d[5] = t.f;
    t.i = v.w << 16;              d[6] = t.f;
    t.i = v.w & (int)0xffff0000;  d[7] = t.f;
}
__device__ __forceinline__ int4 pack8(const float* a) {
    int4 o;
    o.x = packbf(a[0], a[1]); o.y = packbf(a[2], a[3]);
    o.z = packbf(a[4], a[5]); o.w = packbf(a[6], a[7]);
    return o;
}

// ---------------------------------------------------------------------------
// CSR bucket fill (1 atomic slot-claim per edge; memory-side atomic bound).
// ---------------------------------------------------------------------------
__global__ __launch_bounds__(256) void k_fill(
    const int* __restrict__ ei, int* __restrict__ cnt,
    unsigned short* __restrict__ csr, int* __restrict__ ovfc, int* __restrict__ ovf)
{
    int e = blockIdx.x * 256 + threadIdx.x;
    if (e >= EDGES) return;
    int src = __builtin_nontemporal_load(ei + e);
    int dst = __builtin_nontemporal_load(ei + EDGES + e);
    int slot = atomicAdd(&cnt[dst], 1);
    if (slot < CAP) csr[(long)dst * CAP + slot] = (unsigned short)src;
    else { int o = atomicAdd(ovfc, 1); if (o < OVFMAX) ovf[o] = (dst << 16) | src; }
}

// ---------------------------------------------------------------------------
// Half-plane gather: one 3.2 MB plane [NODES][32] bf16 is the ONLY random
// global read -> chip-wide hot set fits each XCD's 4 MB L2 (temporal
// residency). csr index rows are staged to LDS (coalesced, padded rows), so
// they don't compete for L2. 64 nodes/block, 4 lanes/node x 8 feats (16B
// loads), 8 edges in flight. Writes agg[n][halfsel*32 + 0..31] bf16.
// ---------------------------------------------------------------------------
__global__ __launch_bounds__(256) void k_gather_half(
    const int* __restrict__ cnt, const unsigned short* __restrict__ csr,
    const int* __restrict__ ovfc, const int* __restrict__ ovf,
    const bfraw* __restrict__ plane,          // [NODES][32] bf16
    bfraw* __restrict__ agg, int halfsel)     // [NODES][64] bf16
{
    __shared__ unsigned short sCsr[64 * CROW];   // 9.2 KB (padded rows)
    __shared__ int sCnt[64];

    const int base = blockIdx.x * 64;

    // stage csr bucket rows (coalesced 16B; 512 int4s over 256 threads)
    for (int i = threadIdx.x; i < 512; i += 256) {
        int r = i >> 3;                 // 8 int4 per 128B row
        int c = (i & 7) << 3;           // u16 column
        long rr = base + r; if (rr >= NODES) rr = NODES - 1;
        *(int4*)(sCsr + r * CROW + c) = *(const int4*)(csr + rr * CAP + c);
    }
    if (threadIdx.x < 64) {
        int nn = base + threadIdx.x;
        sCnt[threadIdx.x] = (nn < NODES) ? cnt[nn] : 0;
    }
    // pre-warm: stream a sequential ~4KB slice of the plane (782 blocks
    // cover the full 3.2MB once chip-wide; rest arrives via first-touch)
    float dummy = 0.f;
    {
        long s = (long)blockIdx.x * 2048 + (long)threadIdx.x * 8;
        if (s + 8 <= (long)NODES * HALF) {
            int4 a = *(const int4*)(plane + s);
            union { int i; float f; } t; t.i = a.x << 16;
            dummy = t.f;   // finite; folded below with *0.0f
        }
    }
    __syncthreads();

    const int row  = threadIdx.x >> 2;       // 0..63
    const int q    = (threadIdx.x & 3) * 8;  // feat offset in half: 0,8,16,24
    const int n    = base + row;
    int cn = sCnt[row]; if (cn > CAP) cn = CAP;
    const unsigned short* crow = sCsr + row * CROW;

    float acc[8] = {0.f, 0.f, 0.f, 0.f, 0.f, 0.f, 0.f, 0.f};
    for (int i = 0; i < cn; i += 8) {
        int4 ia = *(const int4*)(crow + i);      // 8 u16 slots from LDS
        int rem = cn - i;                        // >= 1
        int idx[8];
        idx[0] = ia.x & 0xffff; idx[1] = ((unsigned)ia.x) >> 16;
        idx[2] = ia.y & 0xffff; idx[3] = ((unsigned)ia.y) >> 16;
        idx[4] = ia.z & 0xffff; idx[5] = ((unsigned)ia.z) >> 16;
        idx[6] = ia.w & 0xffff; idx[7] = ((unsigned)ia.w) >> 16;
        int4 v[8];
        #pragma unroll
        for (int j = 0; j < 8; j++) {
            int s_ = (j < rem) ? idx[j] : idx[0];   // never use garbage as address
            v[j] = *(const int4*)(plane + (long)s_ * HALF + q);
        }
        #pragma unroll
        for (int j = 0; j < 8; j++) addv8(acc, v[j], (j < rem) ? 1.f : 0.f);
    }
    acc[0] += dummy * 0.0f;

    // overflow edges (correctness net; expected count 0 for this input)
    int oc = *ovfc;
    if (oc > 0) {
        if (oc > OVFMAX) oc = OVFMAX;
        for (int t = 0; t < oc; t++) {
            int pk = ovf[t];
            if ((pk >> 16) == n) {
                int4 v = *(const int4*)(plane + (long)(pk & 0xffff) * HALF + q);
                addv8(acc, v, 1.f);
            }
        }
    }

    if (n < NODES)
        *(int4*)(agg + (long)n * STATE + halfsel * HALF + q) = pack8(acc);
}

// ---------------------------------------------------------------------------
// state = relu(x @ inW + inb); msg planes = relu(state @ msgW + msgb).
// 32 nodes/block; 25.6 KB LDS (one reused 8.7 KB buffer staged three times).
// ---------------------------------------------------------------------------
__global__ __launch_bounds__(256) void k_in_msg(
    const float* __restrict__ x, const float* __restrict__ inW, const float* __restrict__ inb,
    const float* __restrict__ msgW, const float* __restrict__ msgb,
    float* __restrict__ state, bfraw* __restrict__ msg0, bfraw* __restrict__ msg1)
{
    __shared__ float sW[64 * STATE];        // 16 KB, staged 3x (inW0, inW1, msgW)
    __shared__ float sB[32 * 68];           // 8.7 KB, staged 3x (x0, x1, state)
    __shared__ float sInb[STATE], sMsgb[STATE];

    const int row = threadIdx.x >> 3;           // node in tile
    const int q8  = (threadIdx.x & 7) << 3;     // feature offset (8 wide)
    const int base = blockIdx.x * 32;
    const int n = base + row;

    if (threadIdx.x < STATE) {
        sInb[threadIdx.x]  = inb[threadIdx.x];
        sMsgb[threadIdx.x] = msgb[threadIdx.x];
    }
    for (int i = threadIdx.x; i < 512; i += 256) {
        int r = i >> 4, q = (i & 15) << 2;
        float4 v = make_float4(0.f, 0.f, 0.f, 0.f);
        if (base + r < NODES) v = *(const float4*)(x + (long)(base + r) * FEAT + q);
        *(float4*)(sB + r * 68 + q) = v;
    }
    for (int i = threadIdx.x; i < 1024; i += 256)
        *(float4*)(sW + i * 4) = *(const float4*)(inW + i * 4);
    __syncthreads();

    float a[8];
    #pragma unroll
    for (int j = 0; j < 8; j++) a[j] = sInb[q8 + j];
    const float* xr = sB + row * 68;
    #pragma unroll 8
    for (int k = 0; k < 64; k++) {
        float xv = xr[k];
        float4 w0 = *(const float4*)(sW + k * STATE + q8);
        float4 w1 = *(const float4*)(sW + k * STATE + q8 + 4);
        a[0] += xv * w0.x; a[1] += xv * w0.y; a[2] += xv * w0.z; a[3] += xv * w0.w;
        a[4] += xv * w1.x; a[5] += xv * w1.y; a[6] += xv * w1.z; a[7] += xv * w1.w;
    }
    __syncthreads();
    for (int i = threadIdx.x; i < 512; i += 256) {
        int r = i >> 4, q = (i & 15) << 2;
        float4 v = make_float4(0.f, 0.f, 0.f, 0.f);
        if (base + r < NODES) v = *(const float4*)(x + (long)(base + r) * FEAT + 64 + q);
        *(float4*)(sB + r * 68 + q) = v;
    }
    for (int i = threadIdx.x; i < 1024; i += 256)
        *(float4*)(sW + i * 4) = *(const float4*)(inW + 64 * STATE + i * 4);
    __syncthreads();
    #pragma unroll 8
    for (int k = 0; k < 64; k++) {
        float xv = xr[k];
        float4 w0 = *(const float4*)(sW + k * STATE + q8);
        float4 w1 = *(const float4*)(sW + k * STATE + q8 + 4);
        a[0] += xv * w0.x; a[1] += xv * w0.y; a[2] += xv * w0.z; a[3] += xv * w0.w;
        a[4] += xv * w1.x; a[5] += xv * w1.y; a[6] += xv * w1.z; a[7] += xv * w1.w;
    }
    #pragma unroll
    for (int j = 0; j < 8; j++) a[j] = fmaxf(a[j], 0.f);
    if (n < NODES) {
        *(float4*)(state + (long)n * STATE + q8)     = make_float4(a[0], a[1], a[2], a[3]);
        *(float4*)(state + (long)n * STATE + q8 + 4) = make_float4(a[4], a[5], a[6], a[7]);
    }
    __syncthreads();    // all reads of sB (x1) done before overwrite with state
    *(float4*)(sB + row * 68 + q8)     = make_float4(a[0], a[1], a[2], a[3]);
    *(float4*)(sB + row * 68 + q8 + 4) = make_float4(a[4], a[5], a[6], a[7]);
    for (int i = threadIdx.x; i < 1024; i += 256)
        *(float4*)(sW + i * 4) = *(const float4*)(msgW + i * 4);
    __syncthreads();

    float m[8];
    #pragma unroll
    for (int j = 0; j < 8; j++) m[j] = sMsgb[q8 + j];
    const float* sr = sB + row * 68;
    #pragma unroll 8
    for (int k = 0; k < STATE; k++) {
        float sv = sr[k];
        float4 w0 = *(const float4*)(sW + k * STATE + q8);
        float4 w1 = *(const float4*)(sW + k * STATE + q8 + 4);
        m[0] += sv * w0.x; m[1] += sv * w0.y; m[2] += sv * w0.z; m[3] += sv * w0.w;
        m[4] += sv * w1.x; m[5] += sv * w1.y; m[6] += sv * w1.z; m[7] += sv * w1.w;
    }
    #pragma unroll
    for (int j = 0; j < 8; j++) m[j] = fmaxf(m[j], 0.f);
    if (n < NODES) {
        bfraw* dst = (q8 < HALF) ? (msg0 + (long)n * HALF + q8) : (msg1 + (long)n * HALF + (q8 - HALF));
        *(int4*)dst = pack8(m);
    }
}

// ---------------------------------------------------------------------------
// Dense round tail: s = state + relu(agg @ updW + updb); msg planes =
// relu(s @ msgW + msgb). Streaming; 32 nodes/block.
// ---------------------------------------------------------------------------
__global__ __launch_bounds__(256) void k_upd_msg(
    const bfraw* __restrict__ agg,
    const float* __restrict__ updW, const float* __restrict__ updb,
    const float* __restrict__ msgW, const float* __restrict__ msgb,
    float* __restrict__ state, bfraw* __restrict__ msg0, bfraw* __restrict__ msg1)
{
    __shared__ float sW[64 * STATE];   // 16 KB, reused updW -> msgW
    __shared__ float sUpdb[STATE], sMsgb[STATE];
    __shared__ float sa[32 * 68];      // agg row, then state row (reused)

    const int row = threadIdx.x >> 3;
    const int q8  = (threadIdx.x & 7) << 3;
    const int n = blockIdx.x * 32 + row;

    if (threadIdx.x < STATE) {
        sUpdb[threadIdx.x] = updb[threadIdx.x];
        sMsgb[threadIdx.x] = msgb[threadIdx.x];
    }
    for (int i = threadIdx.x; i < 1024; i += 256)
        *(float4*)(sW + i * 4) = *(const float4*)(updW + i * 4);
    {
        float tmp[8] = {0.f,0.f,0.f,0.f,0.f,0.f,0.f,0.f};
        if (n < NODES) unpack8(tmp, *(const int4*)(agg + (long)n * STATE + q8));
        *(float4*)(sa + row * 68 + q8)     = make_float4(tmp[0], tmp[1], tmp[2], tmp[3]);
        *(float4*)(sa + row * 68 + q8 + 4) = make_float4(tmp[4], tmp[5], tmp[6], tmp[7]);
    }
    __syncthreads();

    float a[8];
    #pragma unroll
    for (int j = 0; j < 8; j++) a[j] = sUpdb[q8 + j];
    const float* ar = sa + row * 68;
    #pragma unroll 8
    for (int k = 0; k < STATE; k++) {
        float av = ar[k];
        float4 w0 = *(const float4*)(sW + k * STATE + q8);
        float4 w1 = *(const float4*)(sW + k * STATE + q8 + 4);
        a[0] += av * w0.x; a[1] += av * w0.y; a[2] += av * w0.z; a[3] += av * w0.w;
        a[4] += av * w1.x; a[5] += av * w1.y; a[6] += av * w1.z; a[7] += av * w1.w;
    }
    #pragma unroll
    for (int j = 0; j < 8; j++) a[j] = fmaxf(a[j], 0.f);
    float s[8] = {0.f,0.f,0.f,0.f,0.f,0.f,0.f,0.f};
    if (n < NODES) {
        float4 st0 = *(const float4*)(state + (long)n * STATE + q8);
        float4 st1 = *(const float4*)(state + (long)n * STATE + q8 + 4);
        s[0] = st0.x + a[0]; s[1] = st0.y + a[1]; s[2] = st0.z + a[2]; s[3] = st0.w + a[3];
        s[4] = st1.x + a[4]; s[5] = st1.y + a[5]; s[6] = st1.z + a[6]; s[7] = st1.w + a[7];
        *(float4*)(state + (long)n * STATE + q8)     = make_float4(s[0], s[1], s[2], s[3]);
        *(float4*)(state + (long)n * STATE + q8 + 4) = make_float4(s[4], s[5], s[6], s[7]);
    }
    __syncthreads();    // matmul1 LDS reads complete before sa overwrite
    *(float4*)(sa + row * 68 + q8)     = make_float4(s[0], s[1], s[2], s[3]);
    *(float4*)(sa + row * 68 + q8 + 4) = make_float4(s[4], s[5], s[6], s[7]);
    for (int i = threadIdx.x; i < 1024; i += 256)
        *(float4*)(sW + i * 4) = *(const float4*)(msgW + i * 4);
    __syncthreads();

    float m[8];
    #pragma unroll
    for (int j = 0; j < 8; j++) m[j] = sMsgb[q8 + j];
    const float* sr = sa + row * 68;
    #pragma unroll 8
    for (int k = 0; k < STATE; k++) {
        float sv = sr[k];
        float4 w0 = *(const float4*)(sW + k * STATE + q8);
        float4 w1 = *(const float4*)(sW + k * STATE + q8 + 4);
        m[0] += sv * w0.x; m[1] += sv * w0.y; m[2] += sv * w0.z; m[3] += sv * w0.w;
        m[4] += sv * w1.x; m[5] += sv * w1.y; m[6] += sv * w1.z; m[7] += sv * w1.w;
    }
    #pragma unroll
    for (int j = 0; j < 8; j++) m[j] = fmaxf(m[j], 0.f);
    if (n < NODES) {
        bfraw* dst = (q8 < HALF) ? (msg0 + (long)n * HALF + q8) : (msg1 + (long)n * HALF + (q8 - HALF));
        *(int4*)dst = pack8(m);
    }
}

// ---------------------------------------------------------------------------
// Last round tail: update + pool (run-length over sorted batch).
// ---------------------------------------------------------------------------
__global__ __launch_bounds__(256) void k_upd_pool(
    const bfraw* __restrict__ agg,
    const float* __restrict__ updW, const float* __restrict__ updb,
    const float* __restrict__ state, const int* __restrict__ batch,
    float* __restrict__ gs)
{
    __shared__ float sW[64 * STATE];
    __shared__ float sUpdb[STATE];
    __shared__ float sa[32 * 68];      // agg row, then pooled-state row (reused)
    __shared__ int   sg[32];

    const int row = threadIdx.x >> 3;
    const int q8  = (threadIdx.x & 7) << 3;
    const int base = blockIdx.x * 32;
    const int n = base + row;

    if (threadIdx.x < STATE) sUpdb[threadIdx.x] = updb[threadIdx.x];
    for (int i = threadIdx.x; i < 1024; i += 256)
        *(float4*)(sW + i * 4) = *(const float4*)(updW + i * 4);
    {
        float tmp[8] = {0.f,0.f,0.f,0.f,0.f,0.f,0.f,0.f};
        if (n < NODES) unpack8(tmp, *(const int4*)(agg + (long)n * STATE + q8));
        *(float4*)(sa + row * 68 + q8)     = make_float4(tmp[0], tmp[1], tmp[2], tmp[3]);
        *(float4*)(sa + row * 68 + q8 + 4) = make_float4(tmp[4], tmp[5], tmp[6], tmp[7]);
    }
    if (threadIdx.x < 32) {
        int nn = base + threadIdx.x;
        sg[threadIdx.x] = batch[nn < NODES ? nn : NODES - 1];
    }
    __syncthreads();

    float a[8];
    #pragma unroll
    for (int j = 0; j < 8; j++) a[j] = sUpdb[q8 + j];
    const float* ar = sa + row * 68;
    #pragma unroll 8
    for (int k = 0; k < STATE; k++) {
        float av = ar[k];
        float4 w0 = *(const float4*)(sW + k * STATE + q8);
        float4 w1 = *(const float4*)(sW + k * STATE + q8 + 4);
        a[0] += av * w0.x; a[1] += av * w0.y; a[2] += av * w0.z; a[3] += av * w0.w;
        a[4] += av * w1.x; a[5] += av * w1.y; a[6] += av * w1.z; a[7] += av * w1.w;
    }
    float s[8] = {0.f,0.f,0.f,0.f,0.f,0.f,0.f,0.f};
    if (n < NODES) {
        float4 st0 = *(const float4*)(state + (long)n * STATE + q8);
        float4 st1 = *(const float4*)(state + (long)n * STATE + q8 + 4);
        s[0] = st0.x + fmaxf(a[0], 0.f); s[1] = st0.y + fmaxf(a[1], 0.f);
        s[2] = st0.z + fmaxf(a[2], 0.f); s[3] = st0.w + fmaxf(a[3], 0.f);
        s[4] = st1.x + fmaxf(a[4], 0.f); s[5] = st1.y + fmaxf(a[5], 0.f);
        s[6] = st1.z + fmaxf(a[6], 0.f); s[7] = st1.w + fmaxf(a[7], 0.f);
    }
    __syncthreads();    // matmul LDS reads complete before sa overwrite
    *(float4*)(sa + row * 68 + q8)     = make_float4(s[0], s[1], s[2], s[3]);
    *(float4*)(sa + row * 68 + q8 + 4) = make_float4(s[4], s[5], s[6], s[7]);
    __syncthreads();

    if (threadIdx.x < STATE) {
        const int f = threadIdx.x;
        float run = sa[f];
        int g = sg[0];
        #pragma unroll
        for (int r = 1; r < 32; r++) {
            int g2 = sg[r];
            float v = sa[r * 68 + f];
            if (g2 != g) {
                atomicAdd(&gs[g * STATE + f], run);
                run = v; g = g2;
            } else {
                run += v;
            }
        }
        atomicAdd(&gs[g * STATE + f], run);
    }
}

// ---------------------------------------------------------------------------
// mean = gs@meanW+b ; std = exp(0.5*clip(gs@lvW+b, -20, 2)) -> out[2,256,32]
// ---------------------------------------------------------------------------
__global__ __launch_bounds__(64) void k_final(
    const float* __restrict__ gs,
    const float* __restrict__ meanW, const float* __restrict__ meanb,
    const float* __restrict__ lvW, const float* __restrict__ lvb,
    float* __restrict__ out)
{
    __shared__ float row[STATE];
    const int g = blockIdx.x;
    const int j = threadIdx.x;
    row[j] = gs[g * STATE + j];
    __syncthreads();
    if (j < M_OUT) {
        float acc = meanb[j];
        #pragma unroll
        for (int k = 0; k < STATE; k++) acc += row[k] * meanW[k * M_OUT + j];
        out[g * M_OUT + j] = acc;
    } else {
        int jj = j - M_OUT;
        float acc = lvb[jj];
        #pragma unroll
        for (int k = 0; k < STATE; k++) acc += row[k] * lvW[k * M_OUT + jj];
        acc = fminf(fmaxf(acc, -20.f), 2.f);
        out[GRAPHS * M_OUT + g * M_OUT + jj] = expf(0.5f * acc);
    }
}

extern "C" void kernel_launch(void* const* d_in, const int* in_sizes, int n_in,
                              void* d_out, int out_size, void* d_ws, size_t ws_size,
                              hipStream_t stream) {
    const float* x     = (const float*)d_in[0];
    const int*   ei    = (const int*)d_in[1];   // [2, E]: row0 = src (gather), row1 = dst (scatter)
    const int*   batch = (const int*)d_in[2];
    const float* inW   = (const float*)d_in[3];
    const float* inb   = (const float*)d_in[4];
    const float* msgW  = (const float*)d_in[5]; // [4,64,64]
    const float* msgb  = (const float*)d_in[6]; // [4,64]
    const float* updW  = (const float*)d_in[7];
    const float* updb  = (const float*)d_in[8];
    const float* meanW = (const float*)d_in[9];
    const float* meanb = (const float*)d_in[10];
    const float* lvW   = (const float*)d_in[11];
    const float* lvb   = (const float*)d_in[12];
    float* out = (float*)d_out;

    const size_t NS   = (size_t)NODES * STATE * sizeof(float);
    const size_t PLB  = (size_t)NODES * HALF * sizeof(bfraw);    // 3.2 MB
    const size_t AGB  = (size_t)NODES * STATE * sizeof(bfraw);   // 6.4 MB
    char* ws = (char*)d_ws;
    size_t off = 0;
    auto alloc = [&](size_t bytes) { void* p = ws + off; off += (bytes + 255) & ~(size_t)255; return p; };
    float* state  = (float*)alloc(NS);
    bfraw* msgA0  = (bfraw*)alloc(PLB);
    bfraw* msgA1  = (bfraw*)alloc(PLB);
    bfraw* msgB0  = (bfraw*)alloc(PLB);
    bfraw* msgB1  = (bfraw*)alloc(PLB);
    bfraw* agg    = (bfraw*)alloc(AGB);
    float* gs     = (float*)alloc((size_t)GRAPHS * STATE * sizeof(float));
    int*   cnt    = (int*)alloc((size_t)NODES * sizeof(int));
    int*   ovfc   = (int*)alloc(256);
    int*   ovf    = (int*)alloc((size_t)OVFMAX * sizeof(int));
    unsigned short* csr = (unsigned short*)alloc((size_t)NODES * CAP * sizeof(unsigned short));

    hipMemsetAsync(cnt, 0, (size_t)NODES * sizeof(int), stream);
    hipMemsetAsync(ovfc, 0, sizeof(int), stream);
    hipMemsetAsync(gs, 0, (size_t)GRAPHS * STATE * sizeof(float), stream);

    k_fill<<<(EDGES + 255) / 256, 256, 0, stream>>>(ei, cnt, csr, ovfc, ovf);
    k_in_msg<<<NT32, 256, 0, stream>>>(x, inW, inb, msgW, msgb, state, msgA0, msgA1);

    bfraw *mi0 = msgA0, *mi1 = msgA1, *mo0 = msgB0, *mo1 = msgB1;
    for (int r = 0; r < ROUNDS; r++) {
        // temporal feature split: one 3.2MB plane hot at a time (L2-resident)
        k_gather_half<<<NT64, 256, 0, stream>>>(cnt, csr, ovfc, ovf, mi0, agg, 0);
        k_gather_half<<<NT64, 256, 0, stream>>>(cnt, csr, ovfc, ovf, mi1, agg, 1);
        if (r < ROUNDS - 1) {
            k_upd_msg<<<NT32, 256, 0, stream>>>(
                agg,
                updW + r * STATE * STATE, updb + r * STATE,
                msgW + (r + 1) * STATE * STATE, msgb + (r + 1) * STATE,
                state, mo0, mo1);
            bfraw* t0 = mi0; mi0 = mo0; mo0 = t0;
            bfraw* t1 = mi1; mi1 = mo1; mo1 = t1;
        } else {
            k_upd_pool<<<NT32, 256, 0, stream>>>(
                agg,
                updW + r * STATE * STATE, updb + r * STATE,
                state, batch, gs);
        }
    }

    k_final<<<GRAPHS, 64, 0, stream>>>(gs, meanW, meanb, lvW, lvb, out);
}

// Round 8
// 290.384 us; speedup vs baseline: 1.3006x; 1.3006x over previous
//
#include <hip/hip_runtime.h>
#include <math.h>

#define NODES  50000
#define EDGES  800000
#define GRAPHS 256
#define FEAT   128
#define STATE  64
#define M_OUT  32
#define ROUNDS 4
#define NT32   ((NODES + 31) / 32)     // 1563 tiles of 32 nodes
#define CAP    64                      // fixed csr bucket capacity (deg~Poisson(16), max~38; 64=12 sigma)
#define OVFMAX 8192                    // overflow list capacity (expected use: 0)
#define NPART  8                       // dst partitions == XCDs
#define PNODES (NODES / NPART)         // 6250 nodes per partition
#define NBP    391                     // blocks per partition: 391*256*8 = 800768 >= EDGES
#define FSTR   (NBP * 256)             // edge stride between a thread's 8 edges

typedef unsigned short bfraw;

__device__ __forceinline__ bfraw f2bf(float f) {
    union { float f; unsigned int i; } v; v.f = f;
    unsigned int r = v.i + 0x7FFF + ((v.i >> 16) & 1); // round-nearest-even
    return (bfraw)(r >> 16);
}
__device__ __forceinline__ int packbf(float lo, float hi) {
    return ((int)f2bf(hi) << 16) | (int)f2bf(lo);
}
__device__ __forceinline__ void addv8(float* acc, int4 v, float m) {
    union { int i; float f; } t;
    t.i = v.x << 16;                  acc[0] += t.f * m;
    t.i = v.x & (int)0xffff0000;      acc[1] += t.f * m;
    t.i = v.y << 16;                  acc[2] += t.f * m;
    t.i = v.y & (int)0xffff0000;      acc[3] += t.f * m;
    t.i = v.z << 16;                  acc[4] += t.f * m;
    t.i = v.z & (int)0xffff0000;      acc[5] += t.f * m;
    t.i = v.w << 16;                  acc[6] += t.f * m;
    t.i = v.w & (int)0xffff0000;      acc[7] += t.f * m;
}
__device__ __forceinline__ int4 pack8(const float* a) {
    int4 o;
    o.x = packbf(a[0], a[1]); o.y = packbf(a[2], a[3]);
    o.z = packbf(a[4], a[5]); o.w = packbf(a[6], a[7]);
    return o;
}

// ---------------------------------------------------------------------------
// XCD-PARTITIONED CSR bucket fill. dst-space is split into 8 ranges; block b
// owns partition p = b & 7, which matches the round-robin blockIdx->XCD
// mapping. Each partition's 391 blocks scan the full edge list (strided,
// coalesced, nontemporal so the stream doesn't evict L2) and keep only edges
// whose dst is in-partition. All atomics + 2B scatter stores then touch only
// that XCD's 800KB csr slice + 25KB cnt slice -> L2-local atomics, csr
// written back once (kills the measured 7x cross-XCD line ping-pong:
// WRITE_SIZE 44.5MB for a ~6MB dirty footprint).
// ---------------------------------------------------------------------------
__global__ __launch_bounds__(256) void k_fill(
    const int* __restrict__ ei, int* __restrict__ cnt,
    unsigned short* __restrict__ csr, int* __restrict__ ovfc, int* __restrict__ ovf)
{
    const int p  = blockIdx.x & 7;             // partition == XCD (heuristic)
    const int c  = blockIdx.x >> 3;            // 0..NBP-1
    const int t  = c * 256 + threadIdx.x;      // 0..FSTR-1
    const int lo = p * PNODES;
    const int hi = (p == NPART - 1) ? NODES : lo + PNODES;

    #pragma unroll
    for (int k = 0; k < 8; k++) {
        int e = t + k * FSTR;
        if (e >= EDGES) continue;
        int dst = __builtin_nontemporal_load(ei + EDGES + e);
        if (dst < lo || dst >= hi) continue;
        int src = __builtin_nontemporal_load(ei + e);
        int slot = atomicAdd(&cnt[dst], 1);
        if (slot < CAP) csr[(long)dst * CAP + slot] = (unsigned short)src;
        else { int o = atomicAdd(ovfc, 1); if (o < OVFMAX) ovf[o] = (dst << 16) | src; }
    }
}

// ---------------------------------------------------------------------------
// Gather (32 nodes / 256 threads). 8 lanes/node, 16B loads, 8 edges in
// flight, one int4 load per 8 u16 indices. Single merged message array
// [NODES][64] bf16: each edge's 8 lanes read one contiguous 128B row.
// Result row lands in sa[row*68 + 0..63].
// ---------------------------------------------------------------------------
__device__ __forceinline__ void gather_to_lds(
    const int* __restrict__ cnt, const unsigned short* __restrict__ csr,
    const int* __restrict__ ovfc, const int* __restrict__ ovf,
    const bfraw* __restrict__ msg, float* __restrict__ sa)
{
    // pre-warm: stream a sequential slice of msg into cache
    float dummy = 0.f;
    {
        long s = (long)blockIdx.x * 2048 + (long)threadIdx.x * 8;
        if (s + 8 <= (long)NODES * STATE) {
            int4 a = *(const int4*)(msg + s);
            union { int i; float f; } t; t.i = a.x << 16;
            dummy = t.f;   // finite; folded below with *0.0f
        }
    }

    const int row = threadIdx.x >> 3;
    const int q   = (threadIdx.x & 7) * 8;          // 0..56
    const int n   = blockIdx.x * 32 + row;

    int cn = (n < NODES) ? cnt[n] : 0;
    if (cn > CAP) cn = CAP;                          // slots beyond CAP went to overflow
    const unsigned short* crow = csr + (long)n * CAP; // 128B-aligned bucket row

    float acc[8] = {0.f, 0.f, 0.f, 0.f, 0.f, 0.f, 0.f, 0.f};
    for (int i = 0; i < cn; i += 8) {
        int4 ia = *(const int4*)(crow + i);          // 8 u16 slots, 16B aligned
        int rem = cn - i;                            // >= 1
        int idx[8];
        idx[0] = ia.x & 0xffff; idx[1] = ((unsigned)ia.x) >> 16;
        idx[2] = ia.y & 0xffff; idx[3] = ((unsigned)ia.y) >> 16;
        idx[4] = ia.z & 0xffff; idx[5] = ((unsigned)ia.z) >> 16;
        idx[6] = ia.w & 0xffff; idx[7] = ((unsigned)ia.w) >> 16;
        int4 v[8];
        #pragma unroll
        for (int j = 0; j < 8; j++) {
            int s_ = (j < rem) ? idx[j] : idx[0];    // never use garbage as address
            v[j] = *(const int4*)(msg + (long)s_ * STATE + q);
        }
        #pragma unroll
        for (int j = 0; j < 8; j++) addv8(acc, v[j], (j < rem) ? 1.f : 0.f);
    }
    acc[0] += dummy * 0.0f;

    // overflow edges (correctness net; expected count 0 for this input)
    int oc = *ovfc;
    if (oc > 0) {
        if (oc > OVFMAX) oc = OVFMAX;
        for (int t = 0; t < oc; t++) {
            int pk = ovf[t];
            if ((pk >> 16) == n) {
                int4 v = *(const int4*)(msg + (long)(pk & 0xffff) * STATE + q);
                addv8(acc, v, 1.f);
            }
        }
    }

    *(float4*)(sa + row * 68 + q)     = make_float4(acc[0], acc[1], acc[2], acc[3]);
    *(float4*)(sa + row * 68 + q + 4) = make_float4(acc[4], acc[5], acc[6], acc[7]);
}

// ---------------------------------------------------------------------------
// state = relu(x @ inW + inb); msg = relu(state @ msgW + msgb).
// 32 nodes/block; 25.6 KB LDS (one reused 8.7 KB buffer staged three times).
// ---------------------------------------------------------------------------
__global__ __launch_bounds__(256) void k_in_msg(
    const float* __restrict__ x, const float* __restrict__ inW, const float* __restrict__ inb,
    const float* __restrict__ msgW, const float* __restrict__ msgb,
    float* __restrict__ state, bfraw* __restrict__ msg)
{
    __shared__ float sW[64 * STATE];        // 16 KB, staged 3x (inW0, inW1, msgW)
    __shared__ float sB[32 * 68];           // 8.7 KB, staged 3x (x0, x1, state)
    __shared__ float sInb[STATE], sMsgb[STATE];

    const int row = threadIdx.x >> 3;           // node in tile
    const int q8  = (threadIdx.x & 7) << 3;     // feature offset (8 wide)
    const int base = blockIdx.x * 32;
    const int n = base + row;

    if (threadIdx.x < STATE) {
        sInb[threadIdx.x]  = inb[threadIdx.x];
        sMsgb[threadIdx.x] = msgb[threadIdx.x];
    }
    // stage x cols 0..63 + inW rows 0..63
    for (int i = threadIdx.x; i < 512; i += 256) {
        int r = i >> 4, q = (i & 15) << 2;
        float4 v = make_float4(0.f, 0.f, 0.f, 0.f);
        if (base + r < NODES) v = *(const float4*)(x + (long)(base + r) * FEAT + q);
        *(float4*)(sB + r * 68 + q) = v;
    }
    for (int i = threadIdx.x; i < 1024; i += 256)
        *(float4*)(sW + i * 4) = *(const float4*)(inW + i * 4);
    __syncthreads();

    float a[8];
    #pragma unroll
    for (int j = 0; j < 8; j++) a[j] = sInb[q8 + j];
    const float* xr = sB + row * 68;
    #pragma unroll 8
    for (int k = 0; k < 64; k++) {
        float xv = xr[k];
        float4 w0 = *(const float4*)(sW + k * STATE + q8);
        float4 w1 = *(const float4*)(sW + k * STATE + q8 + 4);
        a[0] += xv * w0.x; a[1] += xv * w0.y; a[2] += xv * w0.z; a[3] += xv * w0.w;
        a[4] += xv * w1.x; a[5] += xv * w1.y; a[6] += xv * w1.z; a[7] += xv * w1.w;
    }
    __syncthreads();
    // stage x cols 64..127 + inW rows 64..127
    for (int i = threadIdx.x; i < 512; i += 256) {
        int r = i >> 4, q = (i & 15) << 2;
        float4 v = make_float4(0.f, 0.f, 0.f, 0.f);
        if (base + r < NODES) v = *(const float4*)(x + (long)(base + r) * FEAT + 64 + q);
        *(float4*)(sB + r * 68 + q) = v;
    }
    for (int i = threadIdx.x; i < 1024; i += 256)
        *(float4*)(sW + i * 4) = *(const float4*)(inW + 64 * STATE + i * 4);
    __syncthreads();
    #pragma unroll 8
    for (int k = 0; k < 64; k++) {
        float xv = xr[k];
        float4 w0 = *(const float4*)(sW + k * STATE + q8);
        float4 w1 = *(const float4*)(sW + k * STATE + q8 + 4);
        a[0] += xv * w0.x; a[1] += xv * w0.y; a[2] += xv * w0.z; a[3] += xv * w0.w;
        a[4] += xv * w1.x; a[5] += xv * w1.y; a[6] += xv * w1.z; a[7] += xv * w1.w;
    }
    #pragma unroll
    for (int j = 0; j < 8; j++) a[j] = fmaxf(a[j], 0.f);
    if (n < NODES) {
        *(float4*)(state + (long)n * STATE + q8)     = make_float4(a[0], a[1], a[2], a[3]);
        *(float4*)(state + (long)n * STATE + q8 + 4) = make_float4(a[4], a[5], a[6], a[7]);
    }
    __syncthreads();    // all reads of sB (x1) done before overwrite with state
    *(float4*)(sB + row * 68 + q8)     = make_float4(a[0], a[1], a[2], a[3]);
    *(float4*)(sB + row * 68 + q8 + 4) = make_float4(a[4], a[5], a[6], a[7]);
    for (int i = threadIdx.x; i < 1024; i += 256)
        *(float4*)(sW + i * 4) = *(const float4*)(msgW + i * 4);
    __syncthreads();

    float m[8];
    #pragma unroll
    for (int j = 0; j < 8; j++) m[j] = sMsgb[q8 + j];
    const float* sr = sB + row * 68;
    #pragma unroll 8
    for (int k = 0; k < STATE; k++) {
        float sv = sr[k];
        float4 w0 = *(const float4*)(sW + k * STATE + q8);
        float4 w1 = *(const float4*)(sW + k * STATE + q8 + 4);
        m[0] += sv * w0.x; m[1] += sv * w0.y; m[2] += sv * w0.z; m[3] += sv * w0.w;
        m[4] += sv * w1.x; m[5] += sv * w1.y; m[6] += sv * w1.z; m[7] += sv * w1.w;
    }
    #pragma unroll
    for (int j = 0; j < 8; j++) m[j] = fmaxf(m[j], 0.f);
    if (n < NODES)
        *(int4*)(msg + (long)n * STATE + q8) = pack8(m);
}

// ---------------------------------------------------------------------------
// FUSED round kernel: gather -> update -> next message. Aggregate never
// leaves the CU (sa in LDS). 32 nodes / 256 threads (verified structure).
// ---------------------------------------------------------------------------
__global__ __launch_bounds__(256) void k_round_msg(
    const int* __restrict__ cnt, const unsigned short* __restrict__ csr,
    const int* __restrict__ ovfc, const int* __restrict__ ovf,
    const bfraw* __restrict__ msg_in,
    const float* __restrict__ updW, const float* __restrict__ updb,
    const float* __restrict__ msgW, const float* __restrict__ msgb,
    float* __restrict__ state, bfraw* __restrict__ msg_out)
{
    __shared__ float sW[64 * STATE];   // 16 KB, reused updW -> msgW
    __shared__ float sUpdb[STATE], sMsgb[STATE];
    __shared__ float sa[32 * 68];      // agg row, then state row (reused)

    const int row = threadIdx.x >> 3;
    const int q8  = (threadIdx.x & 7) << 3;
    const int n = blockIdx.x * 32 + row;

    if (threadIdx.x < STATE) {
        sUpdb[threadIdx.x] = updb[threadIdx.x];
        sMsgb[threadIdx.x] = msgb[threadIdx.x];
    }
    for (int i = threadIdx.x; i < 1024; i += 256)
        *(float4*)(sW + i * 4) = *(const float4*)(updW + i * 4);

    gather_to_lds(cnt, csr, ovfc, ovf, msg_in, sa);
    __syncthreads();

    // update matmul: a = relu(agg @ updW + updb); s = state + a
    float a[8];
    #pragma unroll
    for (int j = 0; j < 8; j++) a[j] = sUpdb[q8 + j];
    const float* ar = sa + row * 68;
    #pragma unroll 8
    for (int k = 0; k < STATE; k++) {
        float av = ar[k];
        float4 w0 = *(const float4*)(sW + k * STATE + q8);
        float4 w1 = *(const float4*)(sW + k * STATE + q8 + 4);
        a[0] += av * w0.x; a[1] += av * w0.y; a[2] += av * w0.z; a[3] += av * w0.w;
        a[4] += av * w1.x; a[5] += av * w1.y; a[6] += av * w1.z; a[7] += av * w1.w;
    }
    #pragma unroll
    for (int j = 0; j < 8; j++) a[j] = fmaxf(a[j], 0.f);
    float s[8] = {0.f,0.f,0.f,0.f,0.f,0.f,0.f,0.f};
    if (n < NODES) {
        float4 st0 = *(const float4*)(state + (long)n * STATE + q8);
        float4 st1 = *(const float4*)(state + (long)n * STATE + q8 + 4);
        s[0] = st0.x + a[0]; s[1] = st0.y + a[1]; s[2] = st0.z + a[2]; s[3] = st0.w + a[3];
        s[4] = st1.x + a[4]; s[5] = st1.y + a[5]; s[6] = st1.z + a[6]; s[7] = st1.w + a[7];
        *(float4*)(state + (long)n * STATE + q8)     = make_float4(s[0], s[1], s[2], s[3]);
        *(float4*)(state + (long)n * STATE + q8 + 4) = make_float4(s[4], s[5], s[6], s[7]);
    }
    __syncthreads();    // matmul1 LDS reads complete before sa overwrite
    *(float4*)(sa + row * 68 + q8)     = make_float4(s[0], s[1], s[2], s[3]);
    *(float4*)(sa + row * 68 + q8 + 4) = make_float4(s[4], s[5], s[6], s[7]);
    for (int i = threadIdx.x; i < 1024; i += 256)
        *(float4*)(sW + i * 4) = *(const float4*)(msgW + i * 4);
    __syncthreads();

    // message matmul: m = relu(s @ msgW + msgb)
    float m[8];
    #pragma unroll
    for (int j = 0; j < 8; j++) m[j] = sMsgb[q8 + j];
    const float* sr = sa + row * 68;
    #pragma unroll 8
    for (int k = 0; k < STATE; k++) {
        float sv = sr[k];
        float4 w0 = *(const float4*)(sW + k * STATE + q8);
        float4 w1 = *(const float4*)(sW + k * STATE + q8 + 4);
        m[0] += sv * w0.x; m[1] += sv * w0.y; m[2] += sv * w0.z; m[3] += sv * w0.w;
        m[4] += sv * w1.x; m[5] += sv * w1.y; m[6] += sv * w1.z; m[7] += sv * w1.w;
    }
    #pragma unroll
    for (int j = 0; j < 8; j++) m[j] = fmaxf(m[j], 0.f);
    if (n < NODES)
        *(int4*)(msg_out + (long)n * STATE + q8) = pack8(m);
}

// ---------------------------------------------------------------------------
// FUSED last round: gather -> update -> pool (run-length over sorted batch).
// ---------------------------------------------------------------------------
__global__ __launch_bounds__(256) void k_round_pool(
    const int* __restrict__ cnt, const unsigned short* __restrict__ csr,
    const int* __restrict__ ovfc, const int* __restrict__ ovf,
    const bfraw* __restrict__ msg_in,
    const float* __restrict__ updW, const float* __restrict__ updb,
    const float* __restrict__ state, const int* __restrict__ batch,
    float* __restrict__ gs)
{
    __shared__ float sW[64 * STATE];
    __shared__ float sUpdb[STATE];
    __shared__ float sa[32 * 68];      // agg row, then pooled-state row (reused)
    __shared__ int   sg[32];

    const int row = threadIdx.x >> 3;
    const int q8  = (threadIdx.x & 7) << 3;
    const int base = blockIdx.x * 32;
    const int n = base + row;

    if (threadIdx.x < STATE) sUpdb[threadIdx.x] = updb[threadIdx.x];
    for (int i = threadIdx.x; i < 1024; i += 256)
        *(float4*)(sW + i * 4) = *(const float4*)(updW + i * 4);
    if (threadIdx.x < 32) {
        int nn = base + threadIdx.x;
        sg[threadIdx.x] = batch[nn < NODES ? nn : NODES - 1];
    }

    gather_to_lds(cnt, csr, ovfc, ovf, msg_in, sa);
    __syncthreads();

    float a[8];
    #pragma unroll
    for (int j = 0; j < 8; j++) a[j] = sUpdb[q8 + j];
    const float* ar = sa + row * 68;
    #pragma unroll 8
    for (int k = 0; k < STATE; k++) {
        float av = ar[k];
        float4 w0 = *(const float4*)(sW + k * STATE + q8);
        float4 w1 = *(const float4*)(sW + k * STATE + q8 + 4);
        a[0] += av * w0.x; a[1] += av * w0.y; a[2] += av * w0.z; a[3] += av * w0.w;
        a[4] += av * w1.x; a[5] += av * w1.y; a[6] += av * w1.z; a[7] += av * w1.w;
    }
    float s[8] = {0.f,0.f,0.f,0.f,0.f,0.f,0.f,0.f};
    if (n < NODES) {
        float4 st0 = *(const float4*)(state + (long)n * STATE + q8);
        float4 st1 = *(const float4*)(state + (long)n * STATE + q8 + 4);
        s[0] = st0.x + fmaxf(a[0], 0.f); s[1] = st0.y + fmaxf(a[1], 0.f);
        s[2] = st0.z + fmaxf(a[2], 0.f); s[3] = st0.w + fmaxf(a[3], 0.f);
        s[4] = st1.x + fmaxf(a[4], 0.f); s[5] = st1.y + fmaxf(a[5], 0.f);
        s[6] = st1.z + fmaxf(a[6], 0.f); s[7] = st1.w + fmaxf(a[7], 0.f);
    }
    __syncthreads();    // matmul LDS reads complete before sa overwrite
    *(float4*)(sa + row * 68 + q8)     = make_float4(s[0], s[1], s[2], s[3]);
    *(float4*)(sa + row * 68 + q8 + 4) = make_float4(s[4], s[5], s[6], s[7]);
    __syncthreads();

    if (threadIdx.x < STATE) {
        const int f = threadIdx.x;
        float run = sa[f];
        int g = sg[0];
        #pragma unroll
        for (int r = 1; r < 32; r++) {
            int g2 = sg[r];
            float v = sa[r * 68 + f];
            if (g2 != g) {
                atomicAdd(&gs[g * STATE + f], run);
                run = v; g = g2;
            } else {
                run += v;
            }
        }
        atomicAdd(&gs[g * STATE + f], run);
    }
}

// ---------------------------------------------------------------------------
// mean = gs@meanW+b ; std = exp(0.5*clip(gs@lvW+b, -20, 2)) -> out[2,256,32]
// ---------------------------------------------------------------------------
__global__ __launch_bounds__(64) void k_final(
    const float* __restrict__ gs,
    const float* __restrict__ meanW, const float* __restrict__ meanb,
    const float* __restrict__ lvW, const float* __restrict__ lvb,
    float* __restrict__ out)
{
    __shared__ float row[STATE];
    const int g = blockIdx.x;
    const int j = threadIdx.x;
    row[j] = gs[g * STATE + j];
    __syncthreads();
    if (j < M_OUT) {
        float acc = meanb[j];
        #pragma unroll
        for (int k = 0; k < STATE; k++) acc += row[k] * meanW[k * M_OUT + j];
        out[g * M_OUT + j] = acc;
    } else {
        int jj = j - M_OUT;
        float acc = lvb[jj];
        #pragma unroll
        for (int k = 0; k < STATE; k++) acc += row[k] * lvW[k * M_OUT + jj];
        acc = fminf(fmaxf(acc, -20.f), 2.f);
        out[GRAPHS * M_OUT + g * M_OUT + jj] = expf(0.5f * acc);
    }
}

extern "C" void kernel_launch(void* const* d_in, const int* in_sizes, int n_in,
                              void* d_out, int out_size, void* d_ws, size_t ws_size,
                              hipStream_t stream) {
    const float* x     = (const float*)d_in[0];
    const int*   ei    = (const int*)d_in[1];   // [2, E]: row0 = src (gather), row1 = dst (scatter)
    const int*   batch = (const int*)d_in[2];
    const float* inW   = (const float*)d_in[3];
    const float* inb   = (const float*)d_in[4];
    const float* msgW  = (const float*)d_in[5]; // [4,64,64]
    const float* msgb  = (const float*)d_in[6]; // [4,64]
    const float* updW  = (const float*)d_in[7];
    const float* updb  = (const float*)d_in[8];
    const float* meanW = (const float*)d_in[9];
    const float* meanb = (const float*)d_in[10];
    const float* lvW   = (const float*)d_in[11];
    const float* lvb   = (const float*)d_in[12];
    float* out = (float*)d_out;

    const size_t NS   = (size_t)NODES * STATE * sizeof(float);
    const size_t MSGB = (size_t)NODES * STATE * sizeof(bfraw);   // 6.4 MB
    char* ws = (char*)d_ws;
    size_t off = 0;
    auto alloc = [&](size_t bytes) { void* p = ws + off; off += (bytes + 255) & ~(size_t)255; return p; };
    float* state  = (float*)alloc(NS);
    bfraw* msgA   = (bfraw*)alloc(MSGB);
    bfraw* msgB   = (bfraw*)alloc(MSGB);
    float* gs     = (float*)alloc((size_t)GRAPHS * STATE * sizeof(float));
    int*   cnt    = (int*)alloc((size_t)NODES * sizeof(int));
    int*   ovfc   = (int*)alloc(256);
    int*   ovf    = (int*)alloc((size_t)OVFMAX * sizeof(int));
    unsigned short* csr = (unsigned short*)alloc((size_t)NODES * CAP * sizeof(unsigned short));

    hipMemsetAsync(cnt, 0, (size_t)NODES * sizeof(int), stream);
    hipMemsetAsync(ovfc, 0, sizeof(int), stream);
    hipMemsetAsync(gs, 0, (size_t)GRAPHS * STATE * sizeof(float), stream);

    // XCD-partitioned fill: 8 partitions x 391 blocks, partition = bid & 7
    k_fill<<<NBP * NPART, 256, 0, stream>>>(ei, cnt, csr, ovfc, ovf);
    k_in_msg<<<NT32, 256, 0, stream>>>(x, inW, inb, msgW, msgb, state, msgA);

    bfraw *mi = msgA, *mo = msgB;
    for (int r = 0; r < ROUNDS; r++) {
        if (r < ROUNDS - 1) {
            k_round_msg<<<NT32, 256, 0, stream>>>(
                cnt, csr, ovfc, ovf, mi,
                updW + r * STATE * STATE, updb + r * STATE,
                msgW + (r + 1) * STATE * STATE, msgb + (r + 1) * STATE,
                state, mo);
            bfraw* t = mi; mi = mo; mo = t;
        } else {
            k_round_pool<<<NT32, 256, 0, stream>>>(
                cnt, csr, ovfc, ovf, mi,
                updW + r * STATE * STATE, updb + r * STATE,
                state, batch, gs);
        }
    }

    k_final<<<GRAPHS, 64, 0, stream>>>(gs, meanW, meanb, lvW, lvb, out);
}